// Round 6
// baseline (580.624 us; speedup 1.0000x reference)
//
#include <hip/hip_runtime.h>

#define N_NODES 50000
#define EPS 1e-6f
#define SCAN_BLOCKS 196   // 196*256 = 50176 >= N_NODES

// ---------------- Workspace layout ----------------
// cnt    : 50176 ints  (zeroed each call)
// off    : 50176 ints  (off[N] = E total)
// cursor : 50176 ints
// bsum   : 256 ints
// ssrc   : E ints      (src ids grouped by dst)
// mean1  : N*64 floats
// g      : N*64 floats (relu(mean1@W1+b1) @ W2, pre-gather)
//
// NUMERICS CONTRACT (round-4 post-mortem): all float accumulation orders are
// bit-identical to the round-3 kernel that measured absmax 0.03125:
//  - gather neighbor sums: global groups-of-4 with (v0+v1)+(v2+v3), tail sequential
//  - GEMMs: acc init (bias / 0), then fmaf over k ascending, one chain per output
//  - log-softmax: butterfly over feature bits 5..0, epilogue (val-mx)-logf(sm)
// Integer paths (hist/fill/scan) may be restructured freely (exact sums).

// component j of a float4 (j must be a compile-time constant after unroll)
#define COMP(v, j) ((j) == 0 ? (v).x : (j) == 1 ? (v).y : (j) == 2 ? (v).z : (v).w)

// ---- CSR build ----
__global__ __launch_bounds__(256) void hist_kernel(
    const int* __restrict__ dst, int* __restrict__ cnt, int E) {
  int i = blockIdx.x * 256 + threadIdx.x;
  int n4 = E >> 2;
  if (i < n4) {
    int4 d = ((const int4*)dst)[i];
    atomicAdd(&cnt[d.x], 1);
    atomicAdd(&cnt[d.y], 1);
    atomicAdd(&cnt[d.z], 1);
    atomicAdd(&cnt[d.w], 1);
  } else if (i < n4 + (E & 3)) {
    atomicAdd(&cnt[dst[4 * n4 + (i - n4)]], 1);
  }
}

__global__ __launch_bounds__(256) void scan1_kernel(
    const int* __restrict__ cnt, int* __restrict__ bsum) {
  __shared__ int red[4];
  int t = threadIdx.x;
  int i = blockIdx.x * 256 + t;
  int v = (i < N_NODES) ? cnt[i] : 0;
#pragma unroll
  for (int o = 32; o > 0; o >>= 1) v += __shfl_xor(v, o, 64);
  if ((t & 63) == 0) red[t >> 6] = v;
  __syncthreads();
  if (t == 0) bsum[blockIdx.x] = red[0] + red[1] + red[2] + red[3];
}

__global__ __launch_bounds__(256) void scan2_kernel(
    int* __restrict__ bsum, int* __restrict__ off) {
  __shared__ int wsum[4];
  int t = threadIdx.x;
  int v = (t < SCAN_BLOCKS) ? bsum[t] : 0;
  int lane = t & 63, wv = t >> 6;
  int x = v;
#pragma unroll
  for (int d = 1; d < 64; d <<= 1) {
    int y = __shfl_up(x, d, 64);
    if (lane >= d) x += y;
  }
  if (lane == 63) wsum[wv] = x;
  __syncthreads();
  int add = 0;
  for (int w = 0; w < wv; w++) add += wsum[w];
  x += add;
  if (t < SCAN_BLOCKS) bsum[t] = x - v;
  if (t == SCAN_BLOCKS - 1) off[N_NODES] = x;
}

__global__ __launch_bounds__(256) void scan3_kernel(
    const int* __restrict__ cnt, const int* __restrict__ bsum,
    int* __restrict__ off, int* __restrict__ cursor) {
  __shared__ int wsum[4];
  int t = threadIdx.x;
  int i = blockIdx.x * 256 + t;
  int v = (i < N_NODES) ? cnt[i] : 0;
  int lane = t & 63, wv = t >> 6;
  int x = v;
#pragma unroll
  for (int d = 1; d < 64; d <<= 1) {
    int y = __shfl_up(x, d, 64);
    if (lane >= d) x += y;
  }
  if (lane == 63) wsum[wv] = x;
  __syncthreads();
  int add = bsum[blockIdx.x];
  for (int w = 0; w < wv; w++) add += wsum[w];
  int excl = add + x - v;
  if (i < N_NODES) {
    off[i] = excl;
    cursor[i] = excl;
  }
}

__global__ __launch_bounds__(256) void fill_kernel(
    const int* __restrict__ src, const int* __restrict__ dst,
    int* __restrict__ cursor, int* __restrict__ ssrc, int E) {
  int i = blockIdx.x * 256 + threadIdx.x;
  int n4 = E >> 2;
  if (i < n4) {
    int4 d = ((const int4*)dst)[i];
    int4 s = ((const int4*)src)[i];
    int p0 = atomicAdd(&cursor[d.x], 1);
    int p1 = atomicAdd(&cursor[d.y], 1);
    int p2 = atomicAdd(&cursor[d.z], 1);
    int p3 = atomicAdd(&cursor[d.w], 1);
    ssrc[p0] = s.x;
    ssrc[p1] = s.y;
    ssrc[p2] = s.z;
    ssrc[p3] = s.w;
  } else if (i < n4 + (E & 3)) {
    int e = 4 * n4 + (i - n4);
    int pos = atomicAdd(&cursor[dst[e]], 1);
    ssrc[pos] = src[e];
  }
}

// ---- Gather 1 (unchanged from round 5) ----
__global__ __launch_bounds__(256) void gather1_kernel(
    const float* __restrict__ x, const int* __restrict__ off,
    const int* __restrict__ ssrc, float* __restrict__ mean1) {
  int t = threadIdx.x;
  int lane = t & 63;
  int sub = lane >> 4;
  int l16 = lane & 15;
  int node = blockIdx.x * 16 + ((t >> 6) << 2) + sub;
  int srcLane = sub << 4;
  int b = off[node], e = off[node + 1];
  float4 acc = {0.f, 0.f, 0.f, 0.f};
  for (int base = b; base < e; base += 16) {
    int rem = e - base; if (rem > 16) rem = 16;
    int idx = (l16 < rem) ? ssrc[base + l16] : 0;
    int j = 0;
    for (; j + 4 <= rem; j += 4) {
      int s0 = __shfl(idx, srcLane + j, 64);
      int s1 = __shfl(idx, srcLane + j + 1, 64);
      int s2 = __shfl(idx, srcLane + j + 2, 64);
      int s3 = __shfl(idx, srcLane + j + 3, 64);
      float4 v0 = ((const float4*)(x + (size_t)s0 * 64))[l16];
      float4 v1 = ((const float4*)(x + (size_t)s1 * 64))[l16];
      float4 v2 = ((const float4*)(x + (size_t)s2 * 64))[l16];
      float4 v3 = ((const float4*)(x + (size_t)s3 * 64))[l16];
      acc.x += (v0.x + v1.x) + (v2.x + v3.x);
      acc.y += (v0.y + v1.y) + (v2.y + v3.y);
      acc.z += (v0.z + v1.z) + (v2.z + v3.z);
      acc.w += (v0.w + v1.w) + (v2.w + v3.w);
    }
    for (; j < rem; j++) {
      int s = __shfl(idx, srcLane + j, 64);
      float4 v = ((const float4*)(x + (size_t)s * 64))[l16];
      acc.x += v.x; acc.y += v.y; acc.z += v.z; acc.w += v.w;
    }
  }
  float dinv = 1.0f / ((float)(e - b) + EPS);
  float4 o4;
  o4.x = acc.x * dinv; o4.y = acc.y * dinv;
  o4.z = acc.z * dinv; o4.w = acc.w * dinv;
  ((float4*)(mean1 + (size_t)node * 64))[l16] = o4;
}

// ---- Fused MLP v2: register-tiled, weights from global (L1-resident) ----
// 64 rows/block; LDS only for the A tiles (means 17KB + h1 34KB = 51KB ->
// 3 blocks/CU). GEMM1: 4x8 thread tile; GEMM2: 4x4. Each output keeps one
// fmaf chain over ascending k (bit-identical to round 3).
__global__ __launch_bounds__(256) void mlp_fused_kernel(
    const float* __restrict__ mean1, const float* __restrict__ W1,
    const float* __restrict__ b1, const float* __restrict__ W2,
    float* __restrict__ g) {
  __shared__ float sM[64][68];    // +4 pad: 2-way-max bank aliasing on b128
  __shared__ float sH[64][132];
  int t = threadIdx.x;
  int row0 = blockIdx.x * 64;

  // stage means: 1024 float4, 4 per thread (reads may run past N on the last
  // block; that lands in the adjacent ws region — harmless, never stored)
  {
    const float4* M4 = (const float4*)(mean1 + (size_t)row0 * 64);
#pragma unroll
    for (int i = 0; i < 4; i++) {
      int idx = t + 256 * i;
      *(float4*)&sM[idx >> 4][(idx & 15) << 2] = M4[idx];
    }
  }
  __syncthreads();

  int tc = t & 15;
  int tr = t >> 4;

  {  // GEMM1 + relu -> sH : [64x64] @ W1[64x128]
    int c = tc << 3;   // 8 cols
    int r = tr << 2;   // 4 rows
    float acc[4][8];
    float4 bA = *(const float4*)(b1 + c);
    float4 bB = *(const float4*)(b1 + c + 4);
#pragma unroll
    for (int i = 0; i < 4; i++) {
      acc[i][0] = bA.x; acc[i][1] = bA.y; acc[i][2] = bA.z; acc[i][3] = bA.w;
      acc[i][4] = bB.x; acc[i][5] = bB.y; acc[i][6] = bB.z; acc[i][7] = bB.w;
    }
    for (int k = 0; k < 64; k += 4) {
      float4 a[4];
#pragma unroll
      for (int i = 0; i < 4; i++) a[i] = *(const float4*)&sM[r + i][k];
      float4 wA[4], wB[4];
#pragma unroll
      for (int j = 0; j < 4; j++) {
        const float* wrow = W1 + (size_t)(k + j) * 128 + c;
        wA[j] = *(const float4*)wrow;
        wB[j] = *(const float4*)(wrow + 4);
      }
#pragma unroll
      for (int j = 0; j < 4; j++) {
#pragma unroll
        for (int i = 0; i < 4; i++) {
          float av = COMP(a[i], j);
          acc[i][0] = fmaf(av, wA[j].x, acc[i][0]);
          acc[i][1] = fmaf(av, wA[j].y, acc[i][1]);
          acc[i][2] = fmaf(av, wA[j].z, acc[i][2]);
          acc[i][3] = fmaf(av, wA[j].w, acc[i][3]);
          acc[i][4] = fmaf(av, wB[j].x, acc[i][4]);
          acc[i][5] = fmaf(av, wB[j].y, acc[i][5]);
          acc[i][6] = fmaf(av, wB[j].z, acc[i][6]);
          acc[i][7] = fmaf(av, wB[j].w, acc[i][7]);
        }
      }
    }
#pragma unroll
    for (int i = 0; i < 4; i++) {
      float4 h0, h1v;
      h0.x = fmaxf(acc[i][0], 0.f); h0.y = fmaxf(acc[i][1], 0.f);
      h0.z = fmaxf(acc[i][2], 0.f); h0.w = fmaxf(acc[i][3], 0.f);
      h1v.x = fmaxf(acc[i][4], 0.f); h1v.y = fmaxf(acc[i][5], 0.f);
      h1v.z = fmaxf(acc[i][6], 0.f); h1v.w = fmaxf(acc[i][7], 0.f);
      *(float4*)&sH[r + i][c] = h0;
      *(float4*)&sH[r + i][c + 4] = h1v;
    }
  }
  __syncthreads();

  {  // GEMM2 -> g : [64x128] @ W2[128x64]
    int c = tc << 2;   // 4 cols
    int r = tr << 2;   // 4 rows
    float acc[4][4];
#pragma unroll
    for (int i = 0; i < 4; i++)
      acc[i][0] = acc[i][1] = acc[i][2] = acc[i][3] = 0.f;
    for (int k = 0; k < 128; k += 4) {
      float4 a[4];
#pragma unroll
      for (int i = 0; i < 4; i++) a[i] = *(const float4*)&sH[r + i][k];
      float4 w[4];
#pragma unroll
      for (int j = 0; j < 4; j++)
        w[j] = *(const float4*)(W2 + (size_t)(k + j) * 64 + c);
#pragma unroll
      for (int j = 0; j < 4; j++) {
#pragma unroll
        for (int i = 0; i < 4; i++) {
          float av = COMP(a[i], j);
          acc[i][0] = fmaf(av, w[j].x, acc[i][0]);
          acc[i][1] = fmaf(av, w[j].y, acc[i][1]);
          acc[i][2] = fmaf(av, w[j].z, acc[i][2]);
          acc[i][3] = fmaf(av, w[j].w, acc[i][3]);
        }
      }
    }
#pragma unroll
    for (int i = 0; i < 4; i++) {
      int row = row0 + r + i;
      if (row < N_NODES) {
        float4 o4;
        o4.x = acc[i][0]; o4.y = acc[i][1]; o4.z = acc[i][2]; o4.w = acc[i][3];
        *(float4*)(g + (size_t)row * 64 + c) = o4;
      }
    }
  }
}

// ---- Gather 2 + bias + log_softmax (unchanged from round 5) ----
__global__ __launch_bounds__(256) void gather2_kernel(
    const float* __restrict__ g, const int* __restrict__ off,
    const int* __restrict__ ssrc, const float* __restrict__ b2,
    float* __restrict__ out) {
  int t = threadIdx.x;
  int lane = t & 63;
  int sub = lane >> 4;
  int l16 = lane & 15;
  int node = blockIdx.x * 16 + ((t >> 6) << 2) + sub;
  int srcLane = sub << 4;
  int b = off[node], e = off[node + 1];
  float4 acc = {0.f, 0.f, 0.f, 0.f};
  for (int base = b; base < e; base += 16) {
    int rem = e - base; if (rem > 16) rem = 16;
    int idx = (l16 < rem) ? ssrc[base + l16] : 0;
    int j = 0;
    for (; j + 4 <= rem; j += 4) {
      int s0 = __shfl(idx, srcLane + j, 64);
      int s1 = __shfl(idx, srcLane + j + 1, 64);
      int s2 = __shfl(idx, srcLane + j + 2, 64);
      int s3 = __shfl(idx, srcLane + j + 3, 64);
      float4 v0 = ((const float4*)(g + (size_t)s0 * 64))[l16];
      float4 v1 = ((const float4*)(g + (size_t)s1 * 64))[l16];
      float4 v2 = ((const float4*)(g + (size_t)s2 * 64))[l16];
      float4 v3 = ((const float4*)(g + (size_t)s3 * 64))[l16];
      acc.x += (v0.x + v1.x) + (v2.x + v3.x);
      acc.y += (v0.y + v1.y) + (v2.y + v3.y);
      acc.z += (v0.z + v1.z) + (v2.z + v3.z);
      acc.w += (v0.w + v1.w) + (v2.w + v3.w);
    }
    for (; j < rem; j++) {
      int s = __shfl(idx, srcLane + j, 64);
      float4 v = ((const float4*)(g + (size_t)s * 64))[l16];
      acc.x += v.x; acc.y += v.y; acc.z += v.z; acc.w += v.w;
    }
  }
  float dinv = 1.0f / ((float)(e - b) + EPS);
  float4 b2v = ((const float4*)b2)[l16];
  float4 val;
  val.x = acc.x * dinv + b2v.x;
  val.y = acc.y * dinv + b2v.y;
  val.z = acc.z * dinv + b2v.z;
  val.w = acc.w * dinv + b2v.w;

  float4 m = val;
#pragma unroll
  for (int o = 8; o > 0; o >>= 1) {
    m.x = fmaxf(m.x, __shfl_xor(m.x, o, 64));
    m.y = fmaxf(m.y, __shfl_xor(m.y, o, 64));
    m.z = fmaxf(m.z, __shfl_xor(m.z, o, 64));
    m.w = fmaxf(m.w, __shfl_xor(m.w, o, 64));
  }
  float mx = fmaxf(fmaxf(m.x, m.z), fmaxf(m.y, m.w));

  float4 ex;
  ex.x = __expf(val.x - mx);
  ex.y = __expf(val.y - mx);
  ex.z = __expf(val.z - mx);
  ex.w = __expf(val.w - mx);
#pragma unroll
  for (int o = 8; o > 0; o >>= 1) {
    ex.x += __shfl_xor(ex.x, o, 64);
    ex.y += __shfl_xor(ex.y, o, 64);
    ex.z += __shfl_xor(ex.z, o, 64);
    ex.w += __shfl_xor(ex.w, o, 64);
  }
  float sm = (ex.x + ex.z) + (ex.y + ex.w);

  float ls = logf(sm);
  float4 o4;
  o4.x = (val.x - mx) - ls;
  o4.y = (val.y - mx) - ls;
  o4.z = (val.z - mx) - ls;
  o4.w = (val.w - mx) - ls;
  ((float4*)(out + (size_t)node * 64))[l16] = o4;
}

extern "C" void kernel_launch(void* const* d_in, const int* in_sizes, int n_in,
                              void* d_out, int out_size, void* d_ws, size_t ws_size,
                              hipStream_t stream) {
  const float* x   = (const float*)d_in[0];
  const int*   src = (const int*)d_in[1];
  const int*   dst = (const int*)d_in[2];
  const float* W1  = (const float*)d_in[3];
  const float* b1  = (const float*)d_in[4];
  const float* W2  = (const float*)d_in[5];
  const float* b2  = (const float*)d_in[6];
  float* out = (float*)d_out;
  int E = in_sizes[1];

  const int PAD = 50176;  // SCAN_BLOCKS*256
  int* cnt    = (int*)d_ws;
  int* off    = cnt + PAD;
  int* cursor = off + PAD;
  int* bsum   = cursor + PAD;           // 256 ints
  int* ssrc   = bsum + 256;
  float* mean1 = (float*)(ssrc + 800000);
  float* g     = mean1 + (size_t)N_NODES * 64;

  int ntot = (E >> 2) + (E & 3);
  hipMemsetAsync(cnt, 0, (size_t)N_NODES * sizeof(int), stream);
  hist_kernel<<<(ntot + 255) / 256, 256, 0, stream>>>(dst, cnt, E);
  scan1_kernel<<<SCAN_BLOCKS, 256, 0, stream>>>(cnt, bsum);
  scan2_kernel<<<1, 256, 0, stream>>>(bsum, off);
  scan3_kernel<<<SCAN_BLOCKS, 256, 0, stream>>>(cnt, bsum, off, cursor);
  fill_kernel<<<(ntot + 255) / 256, 256, 0, stream>>>(src, dst, cursor, ssrc, E);

  gather1_kernel<<<N_NODES / 16, 256, 0, stream>>>(x, off, ssrc, mean1);
  mlp_fused_kernel<<<(N_NODES + 63) / 64, 256, 0, stream>>>(mean1, W1, b1, W2, g);
  gather2_kernel<<<N_NODES / 16, 256, 0, stream>>>(g, off, ssrc, b2, out);
}

// Round 7
// 255.559 us; speedup vs baseline: 2.2720x; 2.2720x over previous
//
#include <hip/hip_runtime.h>

#define N_NODES 50000
#define EPS 1e-6f
#define SCAN_BLOCKS 196   // 196*256 = 50176 >= N_NODES

// ---------------- Workspace layout ----------------
// cnt    : 50176 ints  (zeroed each call)
// off    : 50176 ints  (off[N] = E total)
// cursor : 50176 ints
// bsum   : 256 ints
// ssrc   : E ints      (src ids grouped by dst)
// mean1  : N*64 floats
// g      : N*64 floats (relu(mean1@W1+b1) @ W2, pre-gather)
//
// NUMERICS CONTRACT (round-4 post-mortem): all float accumulation orders are
// bit-identical to the round-3 kernel that measured absmax 0.03125:
//  - gather neighbor sums: global groups-of-4 with (v0+v1)+(v2+v3), tail sequential
//  - GEMMs: acc init (bias / 0), then fmaf over k ascending, one chain per output
//  - log-softmax: butterfly over feature bits 5..0, epilogue (val-mx)-logf(sm)
// Integer paths (hist/fill/scan) may be restructured freely (exact sums).
//
// SCHEDULE CONTRACT (round-6 post-mortem): constant-trip k-loops containing
// global loads MUST carry #pragma unroll 1 — full unroll hoists all loads,
// VGPR->256, spills to scratch (449 MB FETCH, 6x regression).

// component j of a float4 (j must be a compile-time constant after unroll)
#define COMP(v, j) ((j) == 0 ? (v).x : (j) == 1 ? (v).y : (j) == 2 ? (v).z : (v).w)

// ---- CSR build ----
__global__ __launch_bounds__(256) void hist_kernel(
    const int* __restrict__ dst, int* __restrict__ cnt, int E) {
  int i = blockIdx.x * 256 + threadIdx.x;
  int n4 = E >> 2;
  if (i < n4) {
    int4 d = ((const int4*)dst)[i];
    atomicAdd(&cnt[d.x], 1);
    atomicAdd(&cnt[d.y], 1);
    atomicAdd(&cnt[d.z], 1);
    atomicAdd(&cnt[d.w], 1);
  } else if (i < n4 + (E & 3)) {
    atomicAdd(&cnt[dst[4 * n4 + (i - n4)]], 1);
  }
}

__global__ __launch_bounds__(256) void scan1_kernel(
    const int* __restrict__ cnt, int* __restrict__ bsum) {
  __shared__ int red[4];
  int t = threadIdx.x;
  int i = blockIdx.x * 256 + t;
  int v = (i < N_NODES) ? cnt[i] : 0;
#pragma unroll
  for (int o = 32; o > 0; o >>= 1) v += __shfl_xor(v, o, 64);
  if ((t & 63) == 0) red[t >> 6] = v;
  __syncthreads();
  if (t == 0) bsum[blockIdx.x] = red[0] + red[1] + red[2] + red[3];
}

__global__ __launch_bounds__(256) void scan2_kernel(
    int* __restrict__ bsum, int* __restrict__ off) {
  __shared__ int wsum[4];
  int t = threadIdx.x;
  int v = (t < SCAN_BLOCKS) ? bsum[t] : 0;
  int lane = t & 63, wv = t >> 6;
  int x = v;
#pragma unroll
  for (int d = 1; d < 64; d <<= 1) {
    int y = __shfl_up(x, d, 64);
    if (lane >= d) x += y;
  }
  if (lane == 63) wsum[wv] = x;
  __syncthreads();
  int add = 0;
  for (int w = 0; w < wv; w++) add += wsum[w];
  x += add;
  if (t < SCAN_BLOCKS) bsum[t] = x - v;
  if (t == SCAN_BLOCKS - 1) off[N_NODES] = x;
}

__global__ __launch_bounds__(256) void scan3_kernel(
    const int* __restrict__ cnt, const int* __restrict__ bsum,
    int* __restrict__ off, int* __restrict__ cursor) {
  __shared__ int wsum[4];
  int t = threadIdx.x;
  int i = blockIdx.x * 256 + t;
  int v = (i < N_NODES) ? cnt[i] : 0;
  int lane = t & 63, wv = t >> 6;
  int x = v;
#pragma unroll
  for (int d = 1; d < 64; d <<= 1) {
    int y = __shfl_up(x, d, 64);
    if (lane >= d) x += y;
  }
  if (lane == 63) wsum[wv] = x;
  __syncthreads();
  int add = bsum[blockIdx.x];
  for (int w = 0; w < wv; w++) add += wsum[w];
  int excl = add + x - v;
  if (i < N_NODES) {
    off[i] = excl;
    cursor[i] = excl;
  }
}

__global__ __launch_bounds__(256) void fill_kernel(
    const int* __restrict__ src, const int* __restrict__ dst,
    int* __restrict__ cursor, int* __restrict__ ssrc, int E) {
  int i = blockIdx.x * 256 + threadIdx.x;
  int n4 = E >> 2;
  if (i < n4) {
    int4 d = ((const int4*)dst)[i];
    int4 s = ((const int4*)src)[i];
    int p0 = atomicAdd(&cursor[d.x], 1);
    int p1 = atomicAdd(&cursor[d.y], 1);
    int p2 = atomicAdd(&cursor[d.z], 1);
    int p3 = atomicAdd(&cursor[d.w], 1);
    ssrc[p0] = s.x;
    ssrc[p1] = s.y;
    ssrc[p2] = s.z;
    ssrc[p3] = s.w;
  } else if (i < n4 + (E & 3)) {
    int e = 4 * n4 + (i - n4);
    int pos = atomicAdd(&cursor[dst[e]], 1);
    ssrc[pos] = src[e];
  }
}

// ---- Gather 1 (unchanged) ----
__global__ __launch_bounds__(256) void gather1_kernel(
    const float* __restrict__ x, const int* __restrict__ off,
    const int* __restrict__ ssrc, float* __restrict__ mean1) {
  int t = threadIdx.x;
  int lane = t & 63;
  int sub = lane >> 4;
  int l16 = lane & 15;
  int node = blockIdx.x * 16 + ((t >> 6) << 2) + sub;
  int srcLane = sub << 4;
  int b = off[node], e = off[node + 1];
  float4 acc = {0.f, 0.f, 0.f, 0.f};
  for (int base = b; base < e; base += 16) {
    int rem = e - base; if (rem > 16) rem = 16;
    int idx = (l16 < rem) ? ssrc[base + l16] : 0;
    int j = 0;
    for (; j + 4 <= rem; j += 4) {
      int s0 = __shfl(idx, srcLane + j, 64);
      int s1 = __shfl(idx, srcLane + j + 1, 64);
      int s2 = __shfl(idx, srcLane + j + 2, 64);
      int s3 = __shfl(idx, srcLane + j + 3, 64);
      float4 v0 = ((const float4*)(x + (size_t)s0 * 64))[l16];
      float4 v1 = ((const float4*)(x + (size_t)s1 * 64))[l16];
      float4 v2 = ((const float4*)(x + (size_t)s2 * 64))[l16];
      float4 v3 = ((const float4*)(x + (size_t)s3 * 64))[l16];
      acc.x += (v0.x + v1.x) + (v2.x + v3.x);
      acc.y += (v0.y + v1.y) + (v2.y + v3.y);
      acc.z += (v0.z + v1.z) + (v2.z + v3.z);
      acc.w += (v0.w + v1.w) + (v2.w + v3.w);
    }
    for (; j < rem; j++) {
      int s = __shfl(idx, srcLane + j, 64);
      float4 v = ((const float4*)(x + (size_t)s * 64))[l16];
      acc.x += v.x; acc.y += v.y; acc.z += v.z; acc.w += v.w;
    }
  }
  float dinv = 1.0f / ((float)(e - b) + EPS);
  float4 o4;
  o4.x = acc.x * dinv; o4.y = acc.y * dinv;
  o4.z = acc.z * dinv; o4.w = acc.w * dinv;
  ((float4*)(mean1 + (size_t)node * 64))[l16] = o4;
}

// ---- Fused MLP v3: round-6 tiling, round-7 schedule control ----
// 64 rows/block; LDS: sM 17KB + sH 33KB = 50KB. Weights from global (L1).
// #pragma unroll 1 on both k loops keeps live W loads to one group (~100 VGPR).
__global__ __launch_bounds__(256, 3) void mlp_fused_kernel(
    const float* __restrict__ mean1, const float* __restrict__ W1,
    const float* __restrict__ b1, const float* __restrict__ W2,
    float* __restrict__ g) {
  __shared__ float sM[64][68];
  __shared__ float sH[64][132];
  int t = threadIdx.x;
  int row0 = blockIdx.x * 64;

  {
    const float4* M4 = (const float4*)(mean1 + (size_t)row0 * 64);
#pragma unroll
    for (int i = 0; i < 4; i++) {
      int idx = t + 256 * i;
      *(float4*)&sM[idx >> 4][(idx & 15) << 2] = M4[idx];
    }
  }
  __syncthreads();

  int tc = t & 15;
  int tr = t >> 4;

  {  // GEMM1 + relu -> sH : [64x64] @ W1[64x128]
    int c = tc << 3;   // 8 cols
    int r = tr << 2;   // 4 rows
    float acc[4][8];
    float4 bA = *(const float4*)(b1 + c);
    float4 bB = *(const float4*)(b1 + c + 4);
#pragma unroll
    for (int i = 0; i < 4; i++) {
      acc[i][0] = bA.x; acc[i][1] = bA.y; acc[i][2] = bA.z; acc[i][3] = bA.w;
      acc[i][4] = bB.x; acc[i][5] = bB.y; acc[i][6] = bB.z; acc[i][7] = bB.w;
    }
#pragma unroll 1
    for (int k = 0; k < 64; k += 4) {
      float4 a[4];
#pragma unroll
      for (int i = 0; i < 4; i++) a[i] = *(const float4*)&sM[r + i][k];
      float4 wA[4], wB[4];
#pragma unroll
      for (int j = 0; j < 4; j++) {
        const float* wrow = W1 + (size_t)(k + j) * 128 + c;
        wA[j] = *(const float4*)wrow;
        wB[j] = *(const float4*)(wrow + 4);
      }
#pragma unroll
      for (int j = 0; j < 4; j++) {
#pragma unroll
        for (int i = 0; i < 4; i++) {
          float av = COMP(a[i], j);
          acc[i][0] = fmaf(av, wA[j].x, acc[i][0]);
          acc[i][1] = fmaf(av, wA[j].y, acc[i][1]);
          acc[i][2] = fmaf(av, wA[j].z, acc[i][2]);
          acc[i][3] = fmaf(av, wA[j].w, acc[i][3]);
          acc[i][4] = fmaf(av, wB[j].x, acc[i][4]);
          acc[i][5] = fmaf(av, wB[j].y, acc[i][5]);
          acc[i][6] = fmaf(av, wB[j].z, acc[i][6]);
          acc[i][7] = fmaf(av, wB[j].w, acc[i][7]);
        }
      }
    }
#pragma unroll
    for (int i = 0; i < 4; i++) {
      float4 h0, h1v;
      h0.x = fmaxf(acc[i][0], 0.f); h0.y = fmaxf(acc[i][1], 0.f);
      h0.z = fmaxf(acc[i][2], 0.f); h0.w = fmaxf(acc[i][3], 0.f);
      h1v.x = fmaxf(acc[i][4], 0.f); h1v.y = fmaxf(acc[i][5], 0.f);
      h1v.z = fmaxf(acc[i][6], 0.f); h1v.w = fmaxf(acc[i][7], 0.f);
      *(float4*)&sH[r + i][c] = h0;
      *(float4*)&sH[r + i][c + 4] = h1v;
    }
  }
  __syncthreads();

  {  // GEMM2 -> g : [64x128] @ W2[128x64]
    int c = tc << 2;   // 4 cols
    int r = tr << 2;   // 4 rows
    float acc[4][4];
#pragma unroll
    for (int i = 0; i < 4; i++)
      acc[i][0] = acc[i][1] = acc[i][2] = acc[i][3] = 0.f;
#pragma unroll 1
    for (int k = 0; k < 128; k += 4) {
      float4 a[4];
#pragma unroll
      for (int i = 0; i < 4; i++) a[i] = *(const float4*)&sH[r + i][k];
      float4 w[4];
#pragma unroll
      for (int j = 0; j < 4; j++)
        w[j] = *(const float4*)(W2 + (size_t)(k + j) * 64 + c);
#pragma unroll
      for (int j = 0; j < 4; j++) {
#pragma unroll
        for (int i = 0; i < 4; i++) {
          float av = COMP(a[i], j);
          acc[i][0] = fmaf(av, w[j].x, acc[i][0]);
          acc[i][1] = fmaf(av, w[j].y, acc[i][1]);
          acc[i][2] = fmaf(av, w[j].z, acc[i][2]);
          acc[i][3] = fmaf(av, w[j].w, acc[i][3]);
        }
      }
    }
#pragma unroll
    for (int i = 0; i < 4; i++) {
      int row = row0 + r + i;
      if (row < N_NODES) {
        float4 o4;
        o4.x = acc[i][0]; o4.y = acc[i][1]; o4.z = acc[i][2]; o4.w = acc[i][3];
        *(float4*)(g + (size_t)row * 64 + c) = o4;
      }
    }
  }
}

// ---- Gather 2 + bias + log_softmax (unchanged) ----
__global__ __launch_bounds__(256) void gather2_kernel(
    const float* __restrict__ g, const int* __restrict__ off,
    const int* __restrict__ ssrc, const float* __restrict__ b2,
    float* __restrict__ out) {
  int t = threadIdx.x;
  int lane = t & 63;
  int sub = lane >> 4;
  int l16 = lane & 15;
  int node = blockIdx.x * 16 + ((t >> 6) << 2) + sub;
  int srcLane = sub << 4;
  int b = off[node], e = off[node + 1];
  float4 acc = {0.f, 0.f, 0.f, 0.f};
  for (int base = b; base < e; base += 16) {
    int rem = e - base; if (rem > 16) rem = 16;
    int idx = (l16 < rem) ? ssrc[base + l16] : 0;
    int j = 0;
    for (; j + 4 <= rem; j += 4) {
      int s0 = __shfl(idx, srcLane + j, 64);
      int s1 = __shfl(idx, srcLane + j + 1, 64);
      int s2 = __shfl(idx, srcLane + j + 2, 64);
      int s3 = __shfl(idx, srcLane + j + 3, 64);
      float4 v0 = ((const float4*)(g + (size_t)s0 * 64))[l16];
      float4 v1 = ((const float4*)(g + (size_t)s1 * 64))[l16];
      float4 v2 = ((const float4*)(g + (size_t)s2 * 64))[l16];
      float4 v3 = ((const float4*)(g + (size_t)s3 * 64))[l16];
      acc.x += (v0.x + v1.x) + (v2.x + v3.x);
      acc.y += (v0.y + v1.y) + (v2.y + v3.y);
      acc.z += (v0.z + v1.z) + (v2.z + v3.z);
      acc.w += (v0.w + v1.w) + (v2.w + v3.w);
    }
    for (; j < rem; j++) {
      int s = __shfl(idx, srcLane + j, 64);
      float4 v = ((const float4*)(g + (size_t)s * 64))[l16];
      acc.x += v.x; acc.y += v.y; acc.z += v.z; acc.w += v.w;
    }
  }
  float dinv = 1.0f / ((float)(e - b) + EPS);
  float4 b2v = ((const float4*)b2)[l16];
  float4 val;
  val.x = acc.x * dinv + b2v.x;
  val.y = acc.y * dinv + b2v.y;
  val.z = acc.z * dinv + b2v.z;
  val.w = acc.w * dinv + b2v.w;

  float4 m = val;
#pragma unroll
  for (int o = 8; o > 0; o >>= 1) {
    m.x = fmaxf(m.x, __shfl_xor(m.x, o, 64));
    m.y = fmaxf(m.y, __shfl_xor(m.y, o, 64));
    m.z = fmaxf(m.z, __shfl_xor(m.z, o, 64));
    m.w = fmaxf(m.w, __shfl_xor(m.w, o, 64));
  }
  float mx = fmaxf(fmaxf(m.x, m.z), fmaxf(m.y, m.w));

  float4 ex;
  ex.x = __expf(val.x - mx);
  ex.y = __expf(val.y - mx);
  ex.z = __expf(val.z - mx);
  ex.w = __expf(val.w - mx);
#pragma unroll
  for (int o = 8; o > 0; o >>= 1) {
    ex.x += __shfl_xor(ex.x, o, 64);
    ex.y += __shfl_xor(ex.y, o, 64);
    ex.z += __shfl_xor(ex.z, o, 64);
    ex.w += __shfl_xor(ex.w, o, 64);
  }
  float sm = (ex.x + ex.z) + (ex.y + ex.w);

  float ls = logf(sm);
  float4 o4;
  o4.x = (val.x - mx) - ls;
  o4.y = (val.y - mx) - ls;
  o4.z = (val.z - mx) - ls;
  o4.w = (val.w - mx) - ls;
  ((float4*)(out + (size_t)node * 64))[l16] = o4;
}

extern "C" void kernel_launch(void* const* d_in, const int* in_sizes, int n_in,
                              void* d_out, int out_size, void* d_ws, size_t ws_size,
                              hipStream_t stream) {
  const float* x   = (const float*)d_in[0];
  const int*   src = (const int*)d_in[1];
  const int*   dst = (const int*)d_in[2];
  const float* W1  = (const float*)d_in[3];
  const float* b1  = (const float*)d_in[4];
  const float* W2  = (const float*)d_in[5];
  const float* b2  = (const float*)d_in[6];
  float* out = (float*)d_out;
  int E = in_sizes[1];

  const int PAD = 50176;  // SCAN_BLOCKS*256
  int* cnt    = (int*)d_ws;
  int* off    = cnt + PAD;
  int* cursor = off + PAD;
  int* bsum   = cursor + PAD;           // 256 ints
  int* ssrc   = bsum + 256;
  float* mean1 = (float*)(ssrc + 800000);
  float* g     = mean1 + (size_t)N_NODES * 64;

  int ntot = (E >> 2) + (E & 3);
  hipMemsetAsync(cnt, 0, (size_t)N_NODES * sizeof(int), stream);
  hist_kernel<<<(ntot + 255) / 256, 256, 0, stream>>>(dst, cnt, E);
  scan1_kernel<<<SCAN_BLOCKS, 256, 0, stream>>>(cnt, bsum);
  scan2_kernel<<<1, 256, 0, stream>>>(bsum, off);
  scan3_kernel<<<SCAN_BLOCKS, 256, 0, stream>>>(cnt, bsum, off, cursor);
  fill_kernel<<<(ntot + 255) / 256, 256, 0, stream>>>(src, dst, cursor, ssrc, E);

  gather1_kernel<<<N_NODES / 16, 256, 0, stream>>>(x, off, ssrc, mean1);
  mlp_fused_kernel<<<(N_NODES + 63) / 64, 256, 0, stream>>>(mean1, W1, b1, W2, g);
  gather2_kernel<<<N_NODES / 16, 256, 0, stream>>>(g, off, ssrc, b2, out);
}